// Round 2
// baseline (427.789 us; speedup 1.0000x reference)
//
#include <hip/hip_runtime.h>
#include <math.h>

#define B 8
#define T 200
#define U 50
#define V 1024
#define NCOL (2 * U - 1)   // 50 blank + 49 emit columns per batch

__device__ __forceinline__ float wave_max(float v) {
    #pragma unroll
    for (int off = 32; off > 0; off >>= 1)
        v = fmaxf(v, __shfl_xor(v, off, 64));
    return v;
}
__device__ __forceinline__ float wave_sum(float v) {
    #pragma unroll
    for (int off = 32; off > 0; off >>= 1)
        v += __shfl_xor(v, off, 64);
    return v;
}

// Fused kernel: one block per batch element, 16 waves.
// Phase 1: waves round-robin over the 99 (u, blank/emit) columns; each wave
//   computes the logsumexp over t of h[b,:,u,v] (64 lanes x 4 t-values) and
//   writes the normalized column straight into LDS. No global workspace
//   round-trip, no separate staging pass.
// Phase 2: wave 0 runs the anti-diagonal DP (lane == u) with register
//   prefetch of LDS operands and the loop clamped at the capture diagonal
//   dmax = ti + ui. Per-batch partial written to d_ws[b] (plain store, no
//   init needed); finalize_kernel reduces the 8 partials to the mean.
__global__ __launch_bounds__(1024)
void rnnt_fused(const float* __restrict__ h,
                const int* __restrict__ targets,
                const int* __restrict__ input_lens,
                const int* __restrict__ target_lens,
                float* __restrict__ partials) {
    __shared__ float s_all[NCOL * T];          // 79.2 KB
    const int b = blockIdx.x;
    const int tid = threadIdx.x;               // 0..1023
    const int wv = tid >> 6;                   // 0..15
    const int lane = tid & 63;

    // ---- Phase 1: column LSEs -> LDS ----
    for (int c = wv; c < NCOL; c += 16) {
        const int u = (c >= U) ? c - U : c;
        const int v = (c >= U) ? targets[b * (U - 1) + u] : 0;
        const float* base = h + (size_t)b * T * U * V + (size_t)u * V + v;

        float x[4];
        float m = -INFINITY;
        #pragma unroll
        for (int k = 0; k < 4; ++k) {
            const int t = lane + 64 * k;
            x[k] = (t < T) ? base[(size_t)t * U * V] : -INFINITY;
            m = fmaxf(m, x[k]);
        }
        m = wave_max(m);
        float s = 0.f;
        #pragma unroll
        for (int k = 0; k < 4; ++k)
            s += __expf(x[k] - m);             // -inf contributes 0
        s = wave_sum(s);
        const float lse = m + __logf(s);

        // blank column u lands at row c = u; emit column u at row c = U + u,
        // i.e. offset U*T + u*T — exactly the s_em layout the DP expects.
        float* dst = s_all + c * T;
        #pragma unroll
        for (int k = 0; k < 4; ++k) {
            const int t = lane + 64 * k;
            if (t < T) dst[t] = x[k] - lse;
        }
    }
    __syncthreads();

    // ---- Phase 2: anti-diagonal DP on wave 0 ----
    if (tid >= 64) return;
    const float* s_bl = s_all;                 // [U][T]
    const float* s_em = s_all + U * T;         // [U-1][T]

    const int u = tid;
    const int ti = input_lens[b] - 1;
    const int ui = target_lens[b] - 1;

    // Clamped row pointers so speculative prefetch reads stay in-bounds
    // (values only consumed when the cell predicate is true).
    const int uc = (u < U) ? u : (U - 1);
    const int ue = (u >= 1) ? ((u <= U - 1) ? u - 1 : U - 2) : 0;
    const float* bl_row = s_bl + uc * T;
    const float* em_row = s_em + ue * T;

    const int dmax = ti + ui;                  // capture diagonal
    float a_prev = (u == 0) ? 0.f : -INFINITY;
    float result = (dmax == 0 && u == 0) ? 0.f : -INFINITY;

    auto clampT = [](int x) { return x < 0 ? 0 : (x > T - 1 ? T - 1 : x); };

    // prefetch operands for d = 1
    float bl_c = bl_row[clampT(0 - u)];
    float em_c = em_row[clampT(1 - u)];

    for (int d = 1; d <= dmax; ++d) {
        const float left = __shfl_up(a_prev, 1, 64);
        // prefetch next diagonal's LDS operands (off the dependent chain)
        const float bl_n = bl_row[clampT(d - u)];
        const float em_n = em_row[clampT(d + 1 - u)];
        const int t = d - u;
        const bool cell = (t >= 0) && (t < T) && (u < U);
        const float term1 = (cell && t >= 1) ? a_prev + bl_c : -INFINITY;
        const float term2 = (cell && u >= 1) ? left + em_c : -INFINITY;
        const float mx = fmaxf(term1, term2);
        const float a_new = (mx == -INFINITY)
            ? -INFINITY
            : mx + __logf(1.f + __expf(fminf(term1, term2) - mx));
        if (cell) a_prev = a_new;
        if (d == dmax && u == ui) result = a_new;   // t == ti implied
        bl_c = bl_n;
        em_c = em_n;
    }
    if (u == ui)
        partials[b] = -(result + s_bl[ui * T + ti]);
}

// One wave: mean of the 8 per-batch partials.
__global__ void finalize_kernel(const float* __restrict__ partials,
                                float* __restrict__ out) {
    float s = (threadIdx.x < B) ? partials[threadIdx.x] : 0.f;
    s = wave_sum(s);
    if (threadIdx.x == 0) out[0] = s * (1.f / (float)B);
}

extern "C" void kernel_launch(void* const* d_in, const int* in_sizes, int n_in,
                              void* d_out, int out_size, void* d_ws, size_t ws_size,
                              hipStream_t stream) {
    const float* h = (const float*)d_in[0];
    const int* targets = (const int*)d_in[1];
    const int* input_lens = (const int*)d_in[2];
    const int* target_lens = (const int*)d_in[3];
    float* out = (float*)d_out;
    float* partials = (float*)d_ws;            // B floats

    rnnt_fused<<<B, 1024, 0, stream>>>(h, targets, input_lens, target_lens, partials);
    finalize_kernel<<<1, 64, 0, stream>>>(partials, out);
}

// Round 3
// 397.140 us; speedup vs baseline: 1.0772x; 1.0772x over previous
//
#include <hip/hip_runtime.h>
#include <math.h>

#define B 8
#define T 200
#define U 50
#define V 1024

__device__ __forceinline__ float wave_max(float v) {
    #pragma unroll
    for (int off = 32; off > 0; off >>= 1)
        v = fmaxf(v, __shfl_xor(v, off, 64));
    return v;
}
__device__ __forceinline__ float wave_sum(float v) {
    #pragma unroll
    for (int off = 32; off > 0; off >>= 1)
        v += __shfl_xor(v, off, 64);
    return v;
}

// One 64-lane wave per (b, u, which): logsumexp over t of one column of h
// (v=0 blank, or v=targets[b][u] emit), normalized log-probs written
// t-contiguous to workspace. 800 fully-independent waves spread over the
// whole chip: ~3200 scatter-load instructions in flight -> the 204,800
// one-line gathers drain in a few µs. (Round-2 lesson: fusing this into
// 8 blocks collapsed MLP onto 8 CUs and cost +30 µs.)
__global__ void lse_kernel(const float* __restrict__ h,
                           const int* __restrict__ targets,
                           float* __restrict__ blank_ws,   // [B][U][T]
                           float* __restrict__ emit_ws,    // [B][U-1][T]
                           float* __restrict__ out) {
    const int u = blockIdx.x;
    const int b = blockIdx.y;
    const int which = blockIdx.z;   // 0 = blank, 1 = emit
    const int lane = threadIdx.x;   // 0..63

    if (u == 0 && b == 0 && which == 0 && lane == 0) out[0] = 0.f;
    if (which == 1 && u >= U - 1) return;

    const int v = (which == 0) ? 0 : targets[b * (U - 1) + u];
    const float* base = h + (size_t)b * T * U * V + (size_t)u * V + v;

    float x[4];
    float m = -INFINITY;
    #pragma unroll
    for (int k = 0; k < 4; ++k) {
        const int t = lane + 64 * k;
        x[k] = (t < T) ? base[(size_t)t * U * V] : -INFINITY;
        m = fmaxf(m, x[k]);
    }
    m = wave_max(m);
    float s = 0.f;
    #pragma unroll
    for (int k = 0; k < 4; ++k)
        s += __expf(x[k] - m);      // -inf contributes 0
    s = wave_sum(s);
    const float lse = m + __logf(s);

    float* outp = (which == 0)
        ? blank_ws + ((size_t)b * U + u) * T
        : emit_ws + ((size_t)b * (U - 1) + u) * T;
    #pragma unroll
    for (int k = 0; k < 4; ++k) {
        const int t = lane + 64 * k;
        if (t < T) outp[t] = x[k] - lse;
    }
}

// One block per batch element. Stage the per-batch DP table into LDS with a
// single fused 512-thread float4 loop (79.2 KB < 160 KB/CU), then wave 0 runs
// the anti-diagonal wavefront (lane == u), with:
//   * LDS operands software-prefetched one diagonal ahead into registers
//     (serial chain = shfl_up + VALU only);
//   * loop clamped at the capture diagonal dmax = ti + ui.
// Fused mean: lane ui atomically adds -final/B into out (zeroed by
// lse_kernel, visible via stream ordering).
__global__ __launch_bounds__(512)
void dp_kernel(const float* __restrict__ blank_ws,
               const float* __restrict__ emit_ws,
               const int* __restrict__ input_lens,
               const int* __restrict__ target_lens,
               float* __restrict__ out) {
    __shared__ float s_all[U * T + (U - 1) * T];   // 79.2 KB

    const int b = blockIdx.x;
    const int tid = threadIdx.x;                   // 0..511
    const int ti = input_lens[b] - 1;
    const int ui = target_lens[b] - 1;

    {
        const float4* gb = (const float4*)(blank_ws + (size_t)b * U * T);
        const float4* ge = (const float4*)(emit_ws + (size_t)b * (U - 1) * T);
        float4* s4 = (float4*)s_all;
        constexpr int NB = (U * T) / 4;                    // 2500
        constexpr int NT = (U * T + (U - 1) * T) / 4;      // 4950
        for (int i = tid; i < NT; i += 512)
            s4[i] = (i < NB) ? gb[i] : ge[i - NB];
    }
    __syncthreads();

    if (tid >= 64) return;                // wave 0 only
    const float* s_bl = s_all;            // [U][T]
    const float* s_em = s_all + U * T;    // [U-1][T]

    const int u = tid;
    // Clamped row pointers so speculative prefetch reads stay inside the
    // arrays (values only consumed when the cell predicate is true).
    const int uc = (u < U) ? u : (U - 1);
    const int ue = (u >= 1) ? ((u <= U - 1) ? u - 1 : U - 2) : 0;
    const float* bl_row = s_bl + uc * T;
    const float* em_row = s_em + ue * T;

    const int dmax = ti + ui;             // capture diagonal
    float a_prev = (u == 0) ? 0.f : -INFINITY;
    float result = (dmax == 0 && u == 0) ? 0.f : -INFINITY;

    auto clampT = [](int x) { return x < 0 ? 0 : (x > T - 1 ? T - 1 : x); };

    // prefetch operands for d = 1
    float bl_c = bl_row[clampT(0 - u)];
    float em_c = em_row[clampT(1 - u)];

    for (int d = 1; d <= dmax; ++d) {
        const float left = __shfl_up(a_prev, 1, 64);
        // prefetch next diagonal's LDS operands (off the dependent chain)
        const float bl_n = bl_row[clampT(d - u)];
        const float em_n = em_row[clampT(d + 1 - u)];
        const int t = d - u;
        const bool cell = (t >= 0) && (t < T) && (u < U);
        const float term1 = (cell && t >= 1) ? a_prev + bl_c : -INFINITY;
        const float term2 = (cell && u >= 1) ? left + em_c : -INFINITY;
        const float mx = fmaxf(term1, term2);
        const float a_new = (mx == -INFINITY)
            ? -INFINITY
            : mx + __logf(1.f + __expf(fminf(term1, term2) - mx));
        if (cell) a_prev = a_new;
        if (d == dmax && u == ui) result = a_new;   // t == ti implied
        bl_c = bl_n;
        em_c = em_n;
    }
    if (u == ui)
        atomicAdd(out, -(result + s_bl[ui * T + ti]) * (1.f / (float)B));
}

extern "C" void kernel_launch(void* const* d_in, const int* in_sizes, int n_in,
                              void* d_out, int out_size, void* d_ws, size_t ws_size,
                              hipStream_t stream) {
    const float* h = (const float*)d_in[0];
    const int* targets = (const int*)d_in[1];
    const int* input_lens = (const int*)d_in[2];
    const int* target_lens = (const int*)d_in[3];
    float* out = (float*)d_out;

    float* blank_ws = (float*)d_ws;                   // B*U*T floats
    float* emit_ws = blank_ws + (size_t)B * U * T;    // B*(U-1)*T floats

    dim3 g1(U, B, 2);
    lse_kernel<<<g1, 64, 0, stream>>>(h, targets, blank_ws, emit_ws, out);
    dp_kernel<<<B, 512, 0, stream>>>(blank_ws, emit_ws, input_lens, target_lens, out);
}